// Round 7
// baseline (186.179 us; speedup 1.0000x reference)
//
#include <hip/hip_runtime.h>
#include <math.h>

// ProtoLoss, MI355X (gfx950) — f16-split MFMA, 2-phase pipelined k-loop.
//
// reference:  anchor = mean(x[:,1:,:],1); pos = x[:,0,:]
//   logit[i,j] = -dist2 = s[i,j] + K_i,  s = 2*pos_i.anc_j + b_j,
//   b_j = -|anc_j|^2 + 2e*sum(anc_j).   K_i cancels in log_softmax/argmax.
//   nloss = mean(lse_i - s_ii), prec1 = 100*mean(argmax_j s == i).
// fp32 GEMM emulated as one f16 GEMM with K=384: A = [hi|lo](2*log2e*pos),
// B = [hi|lo](anc).  Everything downstream runs in log2 domain (exp2/log2),
// converted to nats (*ln2) once per row.

#define NROWS  8192
#define DDIM   192
#define KSPL   384            // hi|lo concatenated along K
#define X3     576
#define FEPS   1e-6f
#define LOG2E  1.4426950408889634f
#define LN2    0.6931471805599453f

#define BM 128
#define BN 128
#define BK 64
#define KSTEPS 6              // KSPL / BK
#define NSPLIT 8
#define JRANGE 1024           // NROWS / NSPLIT
#define JTILES 8              // JRANGE / BN
#define NPART  16             // NSPLIT * 2 (wn halves)
#define NCOMB  32             // combine-partial blocks

typedef _Float16 f16;
typedef _Float16 f16x4 __attribute__((ext_vector_type(4)));
typedef _Float16 f16x8 __attribute__((ext_vector_type(8)));
typedef float    f32x4 __attribute__((ext_vector_type(4)));

__device__ __forceinline__ void async_copy16(const void* g, void* l) {
  __builtin_amdgcn_global_load_lds(
      (const __attribute__((address_space(1))) unsigned int*)g,
      (__attribute__((address_space(3))) unsigned int*)l, 16, 0, 0);
}

// ---------- Kernel 1: split x -> (pos_hi|pos_lo)*2log2e, (anc_hi|anc_lo), b --
// one wave per row; lanes 0..47 each own a float4 quad; vectorized 8B stores.
__global__ __launch_bounds__(256) void prep_kernel(const float* __restrict__ x,
                                                   f16* __restrict__ ph,
                                                   f16* __restrict__ ah,
                                                   float* __restrict__ bvec) {
  const int row  = (blockIdx.x * 256 + threadIdx.x) >> 6;
  const int lane = threadIdx.x & 63;
  float an = 0.f, as = 0.f;
  if (lane < 48) {
    const float* xr = x + (size_t)row * X3;
    const int d = lane * 4;
    const float4 p = *(const float4*)(xr + d);
    const float4 u = *(const float4*)(xr + DDIM + d);
    const float4 w = *(const float4*)(xr + 2 * DDIM + d);
    const float a0 = 0.5f * (u.x + w.x), a1 = 0.5f * (u.y + w.y);
    const float a2 = 0.5f * (u.z + w.z), a3 = 0.5f * (u.w + w.w);
    an = a0 * a0 + a1 * a1 + a2 * a2 + a3 * a3;
    as = a0 + a1 + a2 + a3;
    const float C2 = 2.0f * LOG2E;             // fold 2*log2e into A side
    const float p0 = p.x * C2, p1 = p.y * C2, p2 = p.z * C2, p3 = p.w * C2;
    const f16 h0 = (f16)p0, h1 = (f16)p1, h2 = (f16)p2, h3 = (f16)p3;
    f16x4 hv = {h0, h1, h2, h3};
    f16x4 lv = {(f16)(p0 - (float)h0), (f16)(p1 - (float)h1),
                (f16)(p2 - (float)h2), (f16)(p3 - (float)h3)};
    *(f16x4*)(ph + (size_t)row * KSPL + d) = hv;
    *(f16x4*)(ph + (size_t)row * KSPL + DDIM + d) = lv;
    const f16 g0 = (f16)a0, g1 = (f16)a1, g2 = (f16)a2, g3 = (f16)a3;
    f16x4 gv = {g0, g1, g2, g3};
    f16x4 mv = {(f16)(a0 - (float)g0), (f16)(a1 - (float)g1),
                (f16)(a2 - (float)g2), (f16)(a3 - (float)g3)};
    *(f16x4*)(ah + (size_t)row * KSPL + d) = gv;
    *(f16x4*)(ah + (size_t)row * KSPL + DDIM + d) = mv;
  }
  #pragma unroll
  for (int m = 32; m; m >>= 1) {
    an += __shfl_xor(an, m);
    as += __shfl_xor(as, m);
  }
  if (lane == 0) bvec[row] = LOG2E * (-an + 2.0f * FEPS * as);  // log2-domain b_j
}

// ---------- Kernel 2: f16 MFMA GEMM (K=384) + fused online LSE/argmax -------
// grid (64, 8) = 512 blocks = 2/CU balanced.  2-phase pipeline: data for step
// s lives in buf s&1; step s issues stage(s+1) into the other buffer, computes
// buf s&1, then one __syncthreads() (drains the in-flight loads, which had the
// whole compute phase to fly).  Race-free: restage of buf X at step s+1 is
// separated from its last reads (step s-1) by two barriers.
__global__ __launch_bounds__(256, 2) void main_kernel(
    const f16* __restrict__ Ag, const f16* __restrict__ Bg,
    const float* __restrict__ bvec,
    float* __restrict__ pm, float* __restrict__ ps, int* __restrict__ pa,
    float* __restrict__ diag) {
  __shared__ __align__(16) f16 As[2][BM * BK];   // 2 x 16 KB
  __shared__ __align__(16) f16 Bs[2][BN * BK];   // 2 x 16 KB
  const int tid  = threadIdx.x;
  const int lane = tid & 63;
  const int wid  = tid >> 6;
  const int wm = wid >> 1, wn = wid & 1;
  const int lLow = lane & 15, lHi = lane >> 4, l7 = lane & 7;
  const int i0 = blockIdx.x * BM;
  const int split = blockIdx.y;

  // staging geometry: chunk ci = q*4+wid covers LDS rows [ci*8, ci*8+8),
  // lane -> (row = ci*8 + lane>>3, slot = lane&7); source k-offset swizzled
  // so LDS[row][slot] holds global k-chunk (slot ^ (row&7)).
  const int rsub = lane >> 3;
  const int srck = ((lane & 7) ^ rsub) * 8;

  auto stage = [&](int b, int jt, int kc) {
    const int j0 = split * JRANGE + jt * BN;
    #pragma unroll
    for (int q = 0; q < 4; ++q) {
      const int ci  = q * 4 + wid;
      const int row = ci * 8 + rsub;
      async_copy16(Ag + (size_t)(i0 + row) * KSPL + kc + srck, (void*)(&As[b][ci * 512]));
      async_copy16(Bg + (size_t)(j0 + row) * KSPL + kc + srck, (void*)(&Bs[b][ci * 512]));
    }
  };

  float mrun[16], srun[16];
  int   arun[16];
  #pragma unroll
  for (int r = 0; r < 16; ++r) { mrun[r] = -3.0e38f; srun[r] = 0.f; arun[r] = 0; }

  stage(0, 0, 0);
  __syncthreads();                       // prologue drain (once)

  for (int jt = 0; jt < JTILES; ++jt) {
    f32x4 acc[4][4];
    #pragma unroll
    for (int mf = 0; mf < 4; ++mf)
      #pragma unroll
      for (int nf = 0; nf < 4; ++nf) acc[mf][nf] = (f32x4)0.f;

    #pragma unroll
    for (int ks = 0; ks < KSTEPS; ++ks) {
      // issue next-step loads into the other buffer (none at the very end)
      if (!(jt == JTILES - 1 && ks == KSTEPS - 1)) {
        const int jn = (ks == KSTEPS - 1) ? jt + 1 : jt;
        const int kn = (ks == KSTEPS - 1) ? 0 : (ks + 1) * BK;
        stage((ks + 1) & 1, jn, kn);
      }
      // compute current buffer
      const int b = ks & 1;
      #pragma unroll
      for (int kk = 0; kk < 2; ++kk) {
        const int ksw = ((kk * 4 + lHi) ^ l7) * 8;  // swizzled read chunk
        f16x8 af[4];
        #pragma unroll
        for (int mf = 0; mf < 4; ++mf)
          af[mf] = *(const f16x8*)(&As[b][(wm * 64 + mf * 16 + lLow) * 64 + ksw]);
        #pragma unroll
        for (int nf = 0; nf < 4; ++nf) {
          f16x8 bf = *(const f16x8*)(&Bs[b][(wn * 64 + nf * 16 + lLow) * 64 + ksw]);
          #pragma unroll
          for (int mf = 0; mf < 4; ++mf)
            acc[mf][nf] = __builtin_amdgcn_mfma_f32_16x16x32_f16(af[mf], bf, acc[mf][nf], 0, 0, 0);
        }
      }
      // epilogue on the last k-step, BEFORE the barrier (overlaps loads)
      if (ks == KSTEPS - 1) {
        const int j0 = split * JRANGE + jt * BN;
        float bv[4];
        int   gc[4];
        #pragma unroll
        for (int nf = 0; nf < 4; ++nf) {
          gc[nf] = j0 + wn * 64 + nf * 16 + lLow;
          bv[nf] = bvec[gc[nf]];
        }
        // diagonal tile: j0 == i0  <=>  split*8 + jt == blockIdx.x
        const bool dtile = (split == (int)(blockIdx.x >> 3)) && (jt == (int)(blockIdx.x & 7));
        #pragma unroll
        for (int mf = 0; mf < 4; ++mf) {
          #pragma unroll
          for (int reg = 0; reg < 4; ++reg) {
            const int rs = mf * 4 + reg;
            const int grow = i0 + wm * 64 + mf * 16 + lHi * 4 + reg;
            float v0 = acc[mf][0][reg] + bv[0];   // log2-domain logits
            float v1 = acc[mf][1][reg] + bv[1];
            float v2 = acc[mf][2][reg] + bv[2];
            float v3 = acc[mf][3][reg] + bv[3];
            if (dtile) {
              if (grow == gc[0]) diag[grow] = v0;
              if (grow == gc[1]) diag[grow] = v1;
              if (grow == gc[2]) diag[grow] = v2;
              if (grow == gc[3]) diag[grow] = v3;
            }
            float tm = v0; int tj = gc[0];                // cols ascend with nf:
            if (v1 > tm) { tm = v1; tj = gc[1]; }         // strict > = first max
            if (v2 > tm) { tm = v2; tj = gc[2]; }
            if (v3 > tm) { tm = v3; tj = gc[3]; }
            float nm = fmaxf(tm, mrun[rs]);
            float se = exp2f(v0 - nm) + exp2f(v1 - nm) + exp2f(v2 - nm) + exp2f(v3 - nm);
            srun[rs] = srun[rs] * exp2f(mrun[rs] - nm) + se;
            if (tm > mrun[rs]) arun[rs] = tj;             // tie keeps earlier j
            mrun[rs] = nm;
          }
        }
      }
      __syncthreads();
    }
  }

  // ---- reduce the 16 lanes sharing each row, write partials ----
  #pragma unroll
  for (int rs = 0; rs < 16; ++rs) {
    float mm = mrun[rs], ss = srun[rs];
    int aa = arun[rs];
    #pragma unroll
    for (int d = 1; d < 16; d <<= 1) {
      float om = __shfl_xor(mm, d, 16);
      float os = __shfl_xor(ss, d, 16);
      int   oa = __shfl_xor(aa, d, 16);
      float nm = fmaxf(mm, om);
      ss = ss * exp2f(mm - nm) + os * exp2f(om - nm);
      if (om > mm || (om == mm && oa < aa)) aa = oa;      // min-j on ties
      mm = nm;
    }
    if (lLow == 0) {
      const int grow = i0 + wm * 64 + (rs >> 2) * 16 + lHi * 4 + (rs & 3);
      const int sidx = split * 2 + wn;
      pm[(size_t)sidx * NROWS + grow] = mm;
      ps[(size_t)sidx * NROWS + grow] = ss;
      pa[(size_t)sidx * NROWS + grow] = aa;
    }
  }
}

// ---------- Kernel 3: merge partials per row (32 blocks, 1 row/thread) ------
__global__ __launch_bounds__(256) void combine_partial(
    const float* __restrict__ pm, const float* __restrict__ ps,
    const int* __restrict__ pa, const float* __restrict__ diag,
    float* __restrict__ partL, float* __restrict__ partC) {
  const int i = blockIdx.x * 256 + threadIdx.x;   // NCOMB*256 == NROWS
  // pass 1: global max (and argmax with min-j ties)
  float mm = pm[i];
  int   aa = pa[i];
  #pragma unroll
  for (int s = 1; s < NPART; ++s) {
    float om = pm[(size_t)s * NROWS + i];
    int   oa = pa[(size_t)s * NROWS + i];
    if (om > mm || (om == mm && oa < aa)) { mm = om; aa = oa; }
  }
  // pass 2: sum of rescaled partial sums
  float ss = 0.f;
  #pragma unroll
  for (int s = 0; s < NPART; ++s)
    ss += ps[(size_t)s * NROWS + i] * exp2f(pm[(size_t)s * NROWS + i] - mm);
  float lsum = (mm + log2f(ss) - diag[i]) * LN2;  // back to nats
  float csum = (aa == i) ? 1.0f : 0.0f;
  #pragma unroll
  for (int d = 32; d; d >>= 1) {
    lsum += __shfl_xor(lsum, d);
    csum += __shfl_xor(csum, d);
  }
  __shared__ float wl[4], wc[4];
  int w = threadIdx.x >> 6;
  if ((threadIdx.x & 63) == 0) { wl[w] = lsum; wc[w] = csum; }
  __syncthreads();
  if (threadIdx.x == 0) {
    partL[blockIdx.x] = wl[0] + wl[1] + wl[2] + wl[3];
    partC[blockIdx.x] = wc[0] + wc[1] + wc[2] + wc[3];
  }
}

// ---------- Kernel 4: final scalars ----------
__global__ __launch_bounds__(64) void final_kernel(
    const float* __restrict__ partL, const float* __restrict__ partC,
    float* __restrict__ out) {
  int t = threadIdx.x;
  float l = (t < NCOMB) ? partL[t] : 0.f;
  float c = (t < NCOMB) ? partC[t] : 0.f;
  #pragma unroll
  for (int d = 32; d; d >>= 1) {
    l += __shfl_xor(l, d);
    c += __shfl_xor(c, d);
  }
  if (t == 0) {
    out[0] = l / (float)NROWS;
    out[1] = 100.f * c / (float)NROWS;
  }
}

extern "C" void kernel_launch(void* const* d_in, const int* in_sizes, int n_in,
                              void* d_out, int out_size, void* d_ws, size_t ws_size,
                              hipStream_t stream) {
  const float* x = (const float*)d_in[0];
  float* out = (float*)d_out;

  // workspace layout (~14.3 MB), 256B-aligned slices
  char* ws = (char*)d_ws;
  size_t off = 0;
  auto take = [&](size_t bytes) { void* p = ws + off; off += (bytes + 255) & ~(size_t)255; return p; };
  f16*   ph    = (f16*)take((size_t)NROWS * KSPL * sizeof(f16));
  f16*   ah    = (f16*)take((size_t)NROWS * KSPL * sizeof(f16));
  float* bvec  = (float*)take((size_t)NROWS * sizeof(float));
  float* pm    = (float*)take((size_t)NPART * NROWS * sizeof(float));
  float* ps    = (float*)take((size_t)NPART * NROWS * sizeof(float));
  int*   pa    = (int*)take((size_t)NPART * NROWS * sizeof(int));
  float* diag  = (float*)take((size_t)NROWS * sizeof(float));
  float* partL = (float*)take((size_t)NCOMB * sizeof(float));
  float* partC = (float*)take((size_t)NCOMB * sizeof(float));

  prep_kernel<<<dim3((NROWS * 64) / 256), 256, 0, stream>>>(x, ph, ah, bvec);
  main_kernel<<<dim3(NROWS / BM, NSPLIT), 256, 0, stream>>>(ph, ah, bvec, pm, ps, pa, diag);
  combine_partial<<<dim3(NCOMB), 256, 0, stream>>>(pm, ps, pa, diag, partL, partC);
  final_kernel<<<1, 64, 0, stream>>>(partL, partC, out);
}

// Round 9
// 174.868 us; speedup vs baseline: 1.0647x; 1.0647x over previous
//
#include <hip/hip_runtime.h>
#include <math.h>

// ProtoLoss, MI355X (gfx950) — f16-split MFMA, occupancy-optimized.
//
// reference:  anchor = mean(x[:,1:,:],1); pos = x[:,0,:]
//   logit[i,j] = -dist2 = s[i,j] + K_i,  s = 2*pos_i.anc_j + b_j,
//   b_j = -|anc_j|^2 + 2e*sum(anc_j).   K_i cancels in log_softmax/argmax.
//   nloss = mean(lse_i - s_ii), prec1 = 100*mean(argmax_j s == i).
// fp32 GEMM emulated as one f16 GEMM with K=384: A = [hi|lo](2*log2e*pos),
// B = [hi|lo](anc); downstream in log2 domain, converted to nats per row.
//
// R7 post-mortem: 4x4 microtile => ~164 unified regs => 2 waves/SIMD cap.
// This version: 8 waves/block, 32x64 wave tile => ~110 regs => 4 waves/SIMD.

#define NROWS  8192
#define DDIM   192
#define KSPL   384            // hi|lo concatenated along K
#define X3     576
#define FEPS   1e-6f
#define LOG2E  1.4426950408889634f
#define LN2    0.6931471805599453f

#define BM 128
#define BN 128
#define BK 64
#define NSPLIT 8
#define JRANGE 1024           // NROWS / NSPLIT
#define JTILES 8              // JRANGE / BN
#define NPART  16             // NSPLIT * 2 (wn halves)
#define NCOMB  32             // combine-partial blocks

typedef _Float16 f16;
typedef _Float16 f16x4 __attribute__((ext_vector_type(4)));
typedef _Float16 f16x8 __attribute__((ext_vector_type(8)));
typedef float    f32x4 __attribute__((ext_vector_type(4)));

__device__ __forceinline__ void async_copy16(const void* g, void* l) {
  __builtin_amdgcn_global_load_lds(
      (const __attribute__((address_space(1))) unsigned int*)g,
      (__attribute__((address_space(3))) unsigned int*)l, 16, 0, 0);
}

// ---------- Kernel 1: split x -> (pos_hi|pos_lo)*2log2e, (anc_hi|anc_lo), b --
__global__ __launch_bounds__(256) void prep_kernel(const float* __restrict__ x,
                                                   f16* __restrict__ ph,
                                                   f16* __restrict__ ah,
                                                   float* __restrict__ bvec) {
  const int row  = (blockIdx.x * 256 + threadIdx.x) >> 6;
  const int lane = threadIdx.x & 63;
  float an = 0.f, as = 0.f;
  if (lane < 48) {
    const float* xr = x + (size_t)row * X3;
    const int d = lane * 4;
    const float4 p = *(const float4*)(xr + d);
    const float4 u = *(const float4*)(xr + DDIM + d);
    const float4 w = *(const float4*)(xr + 2 * DDIM + d);
    const float a0 = 0.5f * (u.x + w.x), a1 = 0.5f * (u.y + w.y);
    const float a2 = 0.5f * (u.z + w.z), a3 = 0.5f * (u.w + w.w);
    an = a0 * a0 + a1 * a1 + a2 * a2 + a3 * a3;
    as = a0 + a1 + a2 + a3;
    const float C2 = 2.0f * LOG2E;             // fold 2*log2e into A side
    const float p0 = p.x * C2, p1 = p.y * C2, p2 = p.z * C2, p3 = p.w * C2;
    const f16 h0 = (f16)p0, h1 = (f16)p1, h2 = (f16)p2, h3 = (f16)p3;
    f16x4 hv = {h0, h1, h2, h3};
    f16x4 lv = {(f16)(p0 - (float)h0), (f16)(p1 - (float)h1),
                (f16)(p2 - (float)h2), (f16)(p3 - (float)h3)};
    *(f16x4*)(ph + (size_t)row * KSPL + d) = hv;
    *(f16x4*)(ph + (size_t)row * KSPL + DDIM + d) = lv;
    const f16 g0 = (f16)a0, g1 = (f16)a1, g2 = (f16)a2, g3 = (f16)a3;
    f16x4 gv = {g0, g1, g2, g3};
    f16x4 mv = {(f16)(a0 - (float)g0), (f16)(a1 - (float)g1),
                (f16)(a2 - (float)g2), (f16)(a3 - (float)g3)};
    *(f16x4*)(ah + (size_t)row * KSPL + d) = gv;
    *(f16x4*)(ah + (size_t)row * KSPL + DDIM + d) = mv;
  }
  #pragma unroll
  for (int m = 32; m; m >>= 1) {
    an += __shfl_xor(an, m);
    as += __shfl_xor(as, m);
  }
  if (lane == 0) bvec[row] = LOG2E * (-an + 2.0f * FEPS * as);  // log2-domain
}

// ---------- Kernel 2: f16 MFMA GEMM (K=384) + fused online LSE/argmax -------
// grid (64, 8) = 512 blocks of 512 threads = 2 blocks/CU, 16 waves/CU
// (4 waves/SIMD at <=128 regs).  8 waves as 4(m)x2(n); wave tile 32x64 via
// 2x4 frags of mfma_f32_16x16x32_f16.  Single-buffer LDS (32 KB), R4-proven
// skeleton: [barrier; stage; barrier(drain); compute] -- zero bank conflicts.
__global__ __launch_bounds__(512, 4) void main_kernel(
    const f16* __restrict__ Ag, const f16* __restrict__ Bg,
    const float* __restrict__ bvec,
    float* __restrict__ pm, float* __restrict__ ps, int* __restrict__ pa,
    float* __restrict__ diag) {
  __shared__ __align__(16) f16 As[BM * BK];   // 16 KB
  __shared__ __align__(16) f16 Bs[BN * BK];   // 16 KB
  const int tid  = threadIdx.x;
  const int lane = tid & 63;
  const int wid  = tid >> 6;                  // 0..7
  const int wm = wid >> 1, wn = wid & 1;
  const int lLow = lane & 15, lHi = lane >> 4, l7 = lane & 7;
  const int i0 = blockIdx.x * BM;
  const int split = blockIdx.y;

  // staging: chunk ci covers LDS rows [ci*8, ci*8+8); each wave writes 2
  // A-chunks + 2 B-chunks (ci = q*8 + wid).  lane -> (row = ci*8 + lane>>3,
  // slot = lane&7); source k-offset swizzled so LDS[row][slot] holds global
  // k-chunk (slot ^ (row&7)).
  const int rsub = lane >> 3;
  const int srck = (l7 ^ rsub) * 8;

  float mrun[8], srun[8];
  int   arun[8];
  #pragma unroll
  for (int r = 0; r < 8; ++r) { mrun[r] = -3.0e38f; srun[r] = 0.f; arun[r] = 0; }

  for (int jt = 0; jt < JTILES; ++jt) {
    const int j0 = split * JRANGE + jt * BN;
    f32x4 acc[2][4];
    #pragma unroll
    for (int mf = 0; mf < 2; ++mf)
      #pragma unroll
      for (int nf = 0; nf < 4; ++nf) acc[mf][nf] = (f32x4)0.f;

    for (int kc = 0; kc < KSPL; kc += BK) {
      __syncthreads();                 // previous tile fully consumed
      #pragma unroll
      for (int q = 0; q < 2; ++q) {
        const int ci  = q * 8 + wid;
        const int row = ci * 8 + rsub;
        async_copy16(Ag + (size_t)(i0 + row) * KSPL + kc + srck, (void*)(As + ci * 512));
        async_copy16(Bg + (size_t)(j0 + row) * KSPL + kc + srck, (void*)(Bs + ci * 512));
      }
      __syncthreads();                 // compiler drains vmcnt before barrier
      #pragma unroll
      for (int kk = 0; kk < 2; ++kk) {
        const int ksw = ((kk * 4 + lHi) ^ l7) * 8;  // swizzled read chunk
        f16x8 af[2];
        #pragma unroll
        for (int mf = 0; mf < 2; ++mf)
          af[mf] = *(const f16x8*)(As + (wm * 32 + mf * 16 + lLow) * 64 + ksw);
        #pragma unroll
        for (int nf = 0; nf < 4; ++nf) {
          f16x8 bf = *(const f16x8*)(Bs + (wn * 64 + nf * 16 + lLow) * 64 + ksw);
          #pragma unroll
          for (int mf = 0; mf < 2; ++mf)
            acc[mf][nf] = __builtin_amdgcn_mfma_f32_16x16x32_f16(af[mf], bf, acc[mf][nf], 0, 0, 0);
        }
      }
    }

    // ---- epilogue: fold this 128-wide j-tile into per-lane online state ----
    float bv[4];
    int   gc[4];
    #pragma unroll
    for (int nf = 0; nf < 4; ++nf) {
      gc[nf] = j0 + wn * 64 + nf * 16 + lLow;
      bv[nf] = bvec[gc[nf]];
    }
    // diagonal tile: j0 == i0  <=>  split*8 + jt == blockIdx.x
    const bool dtile = (split == (int)(blockIdx.x >> 3)) && (jt == (int)(blockIdx.x & 7));
    #pragma unroll
    for (int mf = 0; mf < 2; ++mf) {
      #pragma unroll
      for (int reg = 0; reg < 4; ++reg) {
        const int rs = mf * 4 + reg;
        const int grow = i0 + wm * 32 + mf * 16 + lHi * 4 + reg;
        float v0 = acc[mf][0][reg] + bv[0];   // log2-domain logits
        float v1 = acc[mf][1][reg] + bv[1];
        float v2 = acc[mf][2][reg] + bv[2];
        float v3 = acc[mf][3][reg] + bv[3];
        if (dtile) {
          if (grow == gc[0]) diag[grow] = v0;
          if (grow == gc[1]) diag[grow] = v1;
          if (grow == gc[2]) diag[grow] = v2;
          if (grow == gc[3]) diag[grow] = v3;
        }
        float tm = v0; int tj = gc[0];                // cols ascend with nf:
        if (v1 > tm) { tm = v1; tj = gc[1]; }         // strict > = first max
        if (v2 > tm) { tm = v2; tj = gc[2]; }
        if (v3 > tm) { tm = v3; tj = gc[3]; }
        float nm = fmaxf(tm, mrun[rs]);
        float se = exp2f(v0 - nm) + exp2f(v1 - nm) + exp2f(v2 - nm) + exp2f(v3 - nm);
        srun[rs] = srun[rs] * exp2f(mrun[rs] - nm) + se;
        if (tm > mrun[rs]) arun[rs] = tj;             // tie keeps earlier j
        mrun[rs] = nm;
      }
    }
  }

  // ---- reduce the 16 lanes sharing each row, write partials ----
  #pragma unroll
  for (int rs = 0; rs < 8; ++rs) {
    float mm = mrun[rs], ss = srun[rs];
    int aa = arun[rs];
    #pragma unroll
    for (int d = 1; d < 16; d <<= 1) {
      float om = __shfl_xor(mm, d, 16);
      float os = __shfl_xor(ss, d, 16);
      int   oa = __shfl_xor(aa, d, 16);
      float nm = fmaxf(mm, om);
      ss = ss * exp2f(mm - nm) + os * exp2f(om - nm);
      if (om > mm || (om == mm && oa < aa)) aa = oa;      // min-j on ties
      mm = nm;
    }
    if (lLow == 0) {
      const int grow = i0 + wm * 32 + (rs >> 2) * 16 + lHi * 4 + (rs & 3);
      const int sidx = split * 2 + wn;
      pm[(size_t)sidx * NROWS + grow] = mm;
      ps[(size_t)sidx * NROWS + grow] = ss;
      pa[(size_t)sidx * NROWS + grow] = aa;
    }
  }
}

// ---------- Kernel 3: merge partials per row (32 blocks, 1 row/thread) ------
__global__ __launch_bounds__(256) void combine_partial(
    const float* __restrict__ pm, const float* __restrict__ ps,
    const int* __restrict__ pa, const float* __restrict__ diag,
    float* __restrict__ partL, float* __restrict__ partC) {
  const int i = blockIdx.x * 256 + threadIdx.x;   // NCOMB*256 == NROWS
  float mm = pm[i];
  int   aa = pa[i];
  #pragma unroll
  for (int s = 1; s < NPART; ++s) {
    float om = pm[(size_t)s * NROWS + i];
    int   oa = pa[(size_t)s * NROWS + i];
    if (om > mm || (om == mm && oa < aa)) { mm = om; aa = oa; }
  }
  float ss = 0.f;
  #pragma unroll
  for (int s = 0; s < NPART; ++s)
    ss += ps[(size_t)s * NROWS + i] * exp2f(pm[(size_t)s * NROWS + i] - mm);
  float lsum = (mm + log2f(ss) - diag[i]) * LN2;  // back to nats
  float csum = (aa == i) ? 1.0f : 0.0f;
  #pragma unroll
  for (int d = 32; d; d >>= 1) {
    lsum += __shfl_xor(lsum, d);
    csum += __shfl_xor(csum, d);
  }
  __shared__ float wl[4], wc[4];
  int w = threadIdx.x >> 6;
  if ((threadIdx.x & 63) == 0) { wl[w] = lsum; wc[w] = csum; }
  __syncthreads();
  if (threadIdx.x == 0) {
    partL[blockIdx.x] = wl[0] + wl[1] + wl[2] + wl[3];
    partC[blockIdx.x] = wc[0] + wc[1] + wc[2] + wc[3];
  }
}

// ---------- Kernel 4: final scalars ----------
__global__ __launch_bounds__(64) void final_kernel(
    const float* __restrict__ partL, const float* __restrict__ partC,
    float* __restrict__ out) {
  int t = threadIdx.x;
  float l = (t < NCOMB) ? partL[t] : 0.f;
  float c = (t < NCOMB) ? partC[t] : 0.f;
  #pragma unroll
  for (int d = 32; d; d >>= 1) {
    l += __shfl_xor(l, d);
    c += __shfl_xor(c, d);
  }
  if (t == 0) {
    out[0] = l / (float)NROWS;
    out[1] = 100.f * c / (float)NROWS;
  }
}

extern "C" void kernel_launch(void* const* d_in, const int* in_sizes, int n_in,
                              void* d_out, int out_size, void* d_ws, size_t ws_size,
                              hipStream_t stream) {
  const float* x = (const float*)d_in[0];
  float* out = (float*)d_out;

  // workspace layout (~14.3 MB), 256B-aligned slices
  char* ws = (char*)d_ws;
  size_t off = 0;
  auto take = [&](size_t bytes) { void* p = ws + off; off += (bytes + 255) & ~(size_t)255; return p; };
  f16*   ph    = (f16*)take((size_t)NROWS * KSPL * sizeof(f16));
  f16*   ah    = (f16*)take((size_t)NROWS * KSPL * sizeof(f16));
  float* bvec  = (float*)take((size_t)NROWS * sizeof(float));
  float* pm    = (float*)take((size_t)NPART * NROWS * sizeof(float));
  float* ps    = (float*)take((size_t)NPART * NROWS * sizeof(float));
  int*   pa    = (int*)take((size_t)NPART * NROWS * sizeof(int));
  float* diag  = (float*)take((size_t)NROWS * sizeof(float));
  float* partL = (float*)take((size_t)NCOMB * sizeof(float));
  float* partC = (float*)take((size_t)NCOMB * sizeof(float));

  prep_kernel<<<dim3((NROWS * 64) / 256), 256, 0, stream>>>(x, ph, ah, bvec);
  main_kernel<<<dim3(NROWS / BM, NSPLIT), 512, 0, stream>>>(ph, ah, bvec, pm, ps, pa, diag);
  combine_partial<<<dim3(NCOMB), 256, 0, stream>>>(pm, ps, pa, diag, partL, partC);
  final_kernel<<<1, 64, 0, stream>>>(partL, partC, out);
}

// Round 10
// 168.873 us; speedup vs baseline: 1.1025x; 1.0355x over previous
//
#include <hip/hip_runtime.h>
#include <math.h>

// ProtoLoss, MI355X (gfx950) — f16-split MFMA, counted-vmcnt pipelined k-loop.
//
// reference:  anchor = mean(x[:,1:,:],1); pos = x[:,0,:]
//   logit[i,j] = -dist2 = s[i,j] + K_i,  s = 2*pos_i.anc_j + b_j,
//   b_j = -|anc_j|^2 + 2e*sum(anc_j).   K_i cancels in log_softmax/argmax.
//   nloss = mean(lse_i - s_ii), prec1 = 100*mean(argmax_j s == i).
// fp32 GEMM emulated as one f16 GEMM with K=384: A = [hi|lo](2*log2e*pos),
// B = [hi|lo](anc); downstream in log2 domain, nats restored per row.
//
// R9 post-mortem: occupancy was NOT the limiter (35% occ, same 19% MfmaUtil).
// Limiter = per-kstep vmcnt(0) drain (zero load flight time) + LDS BW.
// This version: 2-buffer pipeline with COUNTED s_waitcnt vmcnt(8) — loads for
// step s+1 stay in flight across the whole compute(s) phase; no full drain in
// the main loop (T3+T4 pattern).  Compute layout = R4-benched 4-wave 64x64.

#define NROWS  8192
#define DDIM   192
#define KSPL   384            // hi|lo concatenated along K
#define X3     576
#define FEPS   1e-6f
#define LOG2E  1.4426950408889634f
#define LN2    0.6931471805599453f

#define BM 128
#define BN 128
#define BK 64
#define KSTEPS 6              // KSPL / BK
#define NSPLIT 8
#define JRANGE 1024           // NROWS / NSPLIT
#define JTILES 8              // JRANGE / BN
#define NPART  16             // NSPLIT * 2 (wn halves)
#define NCOMB  32             // combine-partial blocks

typedef _Float16 f16;
typedef _Float16 f16x4 __attribute__((ext_vector_type(4)));
typedef _Float16 f16x8 __attribute__((ext_vector_type(8)));
typedef float    f32x4 __attribute__((ext_vector_type(4)));

__device__ __forceinline__ void async_copy16(const void* g, void* l) {
  __builtin_amdgcn_global_load_lds(
      (const __attribute__((address_space(1))) unsigned int*)g,
      (__attribute__((address_space(3))) unsigned int*)l, 16, 0, 0);
}

// raw barrier with compiler memory fences (no implicit vmcnt(0) drain)
__device__ __forceinline__ void barrier_nofence_drain() {
  asm volatile("" ::: "memory");
  __builtin_amdgcn_s_barrier();
  asm volatile("" ::: "memory");
}

// ---------- Kernel 1: split x -> (pos_hi|pos_lo)*2log2e, (anc_hi|anc_lo), b --
__global__ __launch_bounds__(256) void prep_kernel(const float* __restrict__ x,
                                                   f16* __restrict__ ph,
                                                   f16* __restrict__ ah,
                                                   float* __restrict__ bvec) {
  const int row  = (blockIdx.x * 256 + threadIdx.x) >> 6;
  const int lane = threadIdx.x & 63;
  float an = 0.f, as = 0.f;
  if (lane < 48) {
    const float* xr = x + (size_t)row * X3;
    const int d = lane * 4;
    const float4 p = *(const float4*)(xr + d);
    const float4 u = *(const float4*)(xr + DDIM + d);
    const float4 w = *(const float4*)(xr + 2 * DDIM + d);
    const float a0 = 0.5f * (u.x + w.x), a1 = 0.5f * (u.y + w.y);
    const float a2 = 0.5f * (u.z + w.z), a3 = 0.5f * (u.w + w.w);
    an = a0 * a0 + a1 * a1 + a2 * a2 + a3 * a3;
    as = a0 + a1 + a2 + a3;
    const float C2 = 2.0f * LOG2E;             // fold 2*log2e into A side
    const float p0 = p.x * C2, p1 = p.y * C2, p2 = p.z * C2, p3 = p.w * C2;
    const f16 h0 = (f16)p0, h1 = (f16)p1, h2 = (f16)p2, h3 = (f16)p3;
    f16x4 hv = {h0, h1, h2, h3};
    f16x4 lv = {(f16)(p0 - (float)h0), (f16)(p1 - (float)h1),
                (f16)(p2 - (float)h2), (f16)(p3 - (float)h3)};
    *(f16x4*)(ph + (size_t)row * KSPL + d) = hv;
    *(f16x4*)(ph + (size_t)row * KSPL + DDIM + d) = lv;
    const f16 g0 = (f16)a0, g1 = (f16)a1, g2 = (f16)a2, g3 = (f16)a3;
    f16x4 gv = {g0, g1, g2, g3};
    f16x4 mv = {(f16)(a0 - (float)g0), (f16)(a1 - (float)g1),
                (f16)(a2 - (float)g2), (f16)(a3 - (float)g3)};
    *(f16x4*)(ah + (size_t)row * KSPL + d) = gv;
    *(f16x4*)(ah + (size_t)row * KSPL + DDIM + d) = mv;
  }
  #pragma unroll
  for (int m = 32; m; m >>= 1) {
    an += __shfl_xor(an, m);
    as += __shfl_xor(as, m);
  }
  if (lane == 0) bvec[row] = LOG2E * (-an + 2.0f * FEPS * as);  // log2-domain
}

// ---------- Kernel 2: f16 MFMA GEMM (K=384) + fused online LSE/argmax -------
// grid (64, 8) = 512 blocks of 256 thr (4 waves 2x2, wave tile 64x64, 4x4
// frags).  Pipeline per k-step s (buf p = s&1):
//   barrier A   (all reads of buf 1-p from step s-1 retired)
//   stage(s+1) -> buf 1-p            (8 global_load_lds, stay in flight)
//   s_waitcnt vmcnt(8)               (MY stage(s) loads landed)
//   barrier B   (ALL waves' stage(s) landed)
//   compute(s) from buf p            (16 ds_read_b128 + 32 MFMA)
// No vmcnt(0) in the main loop; loads get a full compute phase to fly.
__global__ __launch_bounds__(256, 2) void main_kernel(
    const f16* __restrict__ Ag, const f16* __restrict__ Bg,
    const float* __restrict__ bvec,
    float* __restrict__ pm, float* __restrict__ ps, int* __restrict__ pa,
    float* __restrict__ diag) {
  __shared__ __align__(16) f16 As[2][BM * BK];   // 2 x 16 KB
  __shared__ __align__(16) f16 Bs[2][BN * BK];   // 2 x 16 KB
  const int tid  = threadIdx.x;
  const int lane = tid & 63;
  const int wid  = tid >> 6;
  const int wm = wid >> 1, wn = wid & 1;
  const int lLow = lane & 15, lHi = lane >> 4, l7 = lane & 7;
  const int i0 = blockIdx.x * BM;
  const int split = blockIdx.y;

  // staging: chunk ci = q*4+wid covers LDS rows [ci*8, ci*8+8); lane ->
  // (row = ci*8 + lane>>3, slot = lane&7); source k pre-swizzled so
  // LDS[row][slot] holds global k-chunk (slot ^ (row&7)).
  const int rsub = lane >> 3;
  const int srck = (l7 ^ rsub) * 8;

  auto stage = [&](int b, int jt, int kc) {
    const int j0 = split * JRANGE + jt * BN;
    #pragma unroll
    for (int q = 0; q < 4; ++q) {
      const int ci  = q * 4 + wid;
      const int row = ci * 8 + rsub;
      async_copy16(Ag + (size_t)(i0 + row) * KSPL + kc + srck, (void*)(&As[b][ci * 512]));
      async_copy16(Bg + (size_t)(j0 + row) * KSPL + kc + srck, (void*)(&Bs[b][ci * 512]));
    }
  };

  float mrun[16], srun[16];
  int   arun[16];
  #pragma unroll
  for (int r = 0; r < 16; ++r) { mrun[r] = -3.0e38f; srun[r] = 0.f; arun[r] = 0; }

  stage(0, 0, 0);                       // prologue: 8 loads in flight

  int p = 0;                            // buffer parity of current step
  for (int jt = 0; jt < JTILES; ++jt) {
    f32x4 acc[4][4];
    #pragma unroll
    for (int mf = 0; mf < 4; ++mf)
      #pragma unroll
      for (int nf = 0; nf < 4; ++nf) acc[mf][nf] = (f32x4)0.f;

    #pragma unroll
    for (int ks = 0; ks < KSTEPS; ++ks) {
      barrier_nofence_drain();          // A: prev step's reads of buf 1-p done

      if (ks < KSTEPS - 1) {
        stage(p ^ 1, jt, (ks + 1) * BK);
        asm volatile("s_waitcnt vmcnt(8)" ::: "memory");   // stage(s) landed
        barrier_nofence_drain();        // B: everyone's stage(s) landed
        // ---- compute step s from buf p ----
        #pragma unroll
        for (int kk = 0; kk < 2; ++kk) {
          const int ksw = ((kk * 4 + lHi) ^ l7) * 8;
          f16x8 af[4];
          #pragma unroll
          for (int mf = 0; mf < 4; ++mf)
            af[mf] = *(const f16x8*)(&As[p][(wm * 64 + mf * 16 + lLow) * 64 + ksw]);
          #pragma unroll
          for (int nf = 0; nf < 4; ++nf) {
            f16x8 bf = *(const f16x8*)(&Bs[p][(wn * 64 + nf * 16 + lLow) * 64 + ksw]);
            #pragma unroll
            for (int mf = 0; mf < 4; ++mf)
              acc[mf][nf] = __builtin_amdgcn_mfma_f32_16x16x32_f16(af[mf], bf, acc[mf][nf], 0, 0, 0);
          }
        }
      } else {
        // epilogue k-step: issue bvec loads + next-jtile stage, counted wait
        const int j0 = split * JRANGE + jt * BN;
        float bv[4];
        int   gc[4];
        #pragma unroll
        for (int nf = 0; nf < 4; ++nf) {
          gc[nf] = j0 + wn * 64 + nf * 16 + lLow;
          bv[nf] = bvec[gc[nf]];                 // 4 VMEM, issued before stage
        }
        if (jt < JTILES - 1) {
          stage(p ^ 1, jt + 1, 0);
          asm volatile("s_waitcnt vmcnt(12)" ::: "memory"); // stage(s) landed
        } else {
          asm volatile("s_waitcnt vmcnt(4)" ::: "memory");  // stage(s) landed
        }
        barrier_nofence_drain();        // B
        #pragma unroll
        for (int kk = 0; kk < 2; ++kk) {
          const int ksw = ((kk * 4 + lHi) ^ l7) * 8;
          f16x8 af[4];
          #pragma unroll
          for (int mf = 0; mf < 4; ++mf)
            af[mf] = *(const f16x8*)(&As[p][(wm * 64 + mf * 16 + lLow) * 64 + ksw]);
          #pragma unroll
          for (int nf = 0; nf < 4; ++nf) {
            f16x8 bf = *(const f16x8*)(&Bs[p][(wn * 64 + nf * 16 + lLow) * 64 + ksw]);
            #pragma unroll
            for (int mf = 0; mf < 4; ++mf)
              acc[mf][nf] = __builtin_amdgcn_mfma_f32_16x16x32_f16(af[mf], bf, acc[mf][nf], 0, 0, 0);
          }
        }
        // ---- fold this 128-wide j-tile into per-lane online state ----
        const bool dtile = (split == (int)(blockIdx.x >> 3)) && (jt == (int)(blockIdx.x & 7));
        #pragma unroll
        for (int mf = 0; mf < 4; ++mf) {
          #pragma unroll
          for (int reg = 0; reg < 4; ++reg) {
            const int rs = mf * 4 + reg;
            const int grow = i0 + wm * 64 + mf * 16 + lHi * 4 + reg;
            float v0 = acc[mf][0][reg] + bv[0];   // log2-domain logits
            float v1 = acc[mf][1][reg] + bv[1];
            float v2 = acc[mf][2][reg] + bv[2];
            float v3 = acc[mf][3][reg] + bv[3];
            if (dtile) {
              if (grow == gc[0]) diag[grow] = v0;
              if (grow == gc[1]) diag[grow] = v1;
              if (grow == gc[2]) diag[grow] = v2;
              if (grow == gc[3]) diag[grow] = v3;
            }
            float tm = v0; int tj = gc[0];                // cols ascend with nf:
            if (v1 > tm) { tm = v1; tj = gc[1]; }         // strict > = first max
            if (v2 > tm) { tm = v2; tj = gc[2]; }
            if (v3 > tm) { tm = v3; tj = gc[3]; }
            float nm = fmaxf(tm, mrun[rs]);
            float se = exp2f(v0 - nm) + exp2f(v1 - nm) + exp2f(v2 - nm) + exp2f(v3 - nm);
            srun[rs] = srun[rs] * exp2f(mrun[rs] - nm) + se;
            if (tm > mrun[rs]) arun[rs] = tj;             // tie keeps earlier j
            mrun[rs] = nm;
          }
        }
      }
      p ^= 1;
    }
  }

  // ---- reduce the 16 lanes sharing each row, write partials ----
  #pragma unroll
  for (int rs = 0; rs < 16; ++rs) {
    float mm = mrun[rs], ss = srun[rs];
    int aa = arun[rs];
    #pragma unroll
    for (int d = 1; d < 16; d <<= 1) {
      float om = __shfl_xor(mm, d, 16);
      float os = __shfl_xor(ss, d, 16);
      int   oa = __shfl_xor(aa, d, 16);
      float nm = fmaxf(mm, om);
      ss = ss * exp2f(mm - nm) + os * exp2f(om - nm);
      if (om > mm || (om == mm && oa < aa)) aa = oa;      // min-j on ties
      mm = nm;
    }
    if (lLow == 0) {
      const int grow = i0 + wm * 64 + (rs >> 2) * 16 + lHi * 4 + (rs & 3);
      const int sidx = split * 2 + wn;
      pm[(size_t)sidx * NROWS + grow] = mm;
      ps[(size_t)sidx * NROWS + grow] = ss;
      pa[(size_t)sidx * NROWS + grow] = aa;
    }
  }
}

// ---------- Kernel 3: merge partials per row (32 blocks, 1 row/thread) ------
__global__ __launch_bounds__(256) void combine_partial(
    const float* __restrict__ pm, const float* __restrict__ ps,
    const int* __restrict__ pa, const float* __restrict__ diag,
    float* __restrict__ partL, float* __restrict__ partC) {
  const int i = blockIdx.x * 256 + threadIdx.x;   // NCOMB*256 == NROWS
  float mm = pm[i];
  int   aa = pa[i];
  #pragma unroll
  for (int s = 1; s < NPART; ++s) {
    float om = pm[(size_t)s * NROWS + i];
    int   oa = pa[(size_t)s * NROWS + i];
    if (om > mm || (om == mm && oa < aa)) { mm = om; aa = oa; }
  }
  float ss = 0.f;
  #pragma unroll
  for (int s = 0; s < NPART; ++s)
    ss += ps[(size_t)s * NROWS + i] * exp2f(pm[(size_t)s * NROWS + i] - mm);
  float lsum = (mm + log2f(ss) - diag[i]) * LN2;  // back to nats
  float csum = (aa == i) ? 1.0f : 0.0f;
  #pragma unroll
  for (int d = 32; d; d >>= 1) {
    lsum += __shfl_xor(lsum, d);
    csum += __shfl_xor(csum, d);
  }
  __shared__ float wl[4], wc[4];
  int w = threadIdx.x >> 6;
  if ((threadIdx.x & 63) == 0) { wl[w] = lsum; wc[w] = csum; }
  __syncthreads();
  if (threadIdx.x == 0) {
    partL[blockIdx.x] = wl[0] + wl[1] + wl[2] + wl[3];
    partC[blockIdx.x] = wc[0] + wc[1] + wc[2] + wc[3];
  }
}

// ---------- Kernel 4: final scalars ----------
__global__ __launch_bounds__(64) void final_kernel(
    const float* __restrict__ partL, const float* __restrict__ partC,
    float* __restrict__ out) {
  int t = threadIdx.x;
  float l = (t < NCOMB) ? partL[t] : 0.f;
  float c = (t < NCOMB) ? partC[t] : 0.f;
  #pragma unroll
  for (int d = 32; d; d >>= 1) {
    l += __shfl_xor(l, d);
    c += __shfl_xor(c, d);
  }
  if (t == 0) {
    out[0] = l / (float)NROWS;
    out[1] = 100.f * c / (float)NROWS;
  }
}

extern "C" void kernel_launch(void* const* d_in, const int* in_sizes, int n_in,
                              void* d_out, int out_size, void* d_ws, size_t ws_size,
                              hipStream_t stream) {
  const float* x = (const float*)d_in[0];
  float* out = (float*)d_out;

  // workspace layout (~14.3 MB), 256B-aligned slices
  char* ws = (char*)d_ws;
  size_t off = 0;
  auto take = [&](size_t bytes) { void* p = ws + off; off += (bytes + 255) & ~(size_t)255; return p; };
  f16*   ph    = (f16*)take((size_t)NROWS * KSPL * sizeof(f16));
  f16*   ah    = (f16*)take((size_t)NROWS * KSPL * sizeof(f16));
  float* bvec  = (float*)take((size_t)NROWS * sizeof(float));
  float* pm    = (float*)take((size_t)NPART * NROWS * sizeof(float));
  float* ps    = (float*)take((size_t)NPART * NROWS * sizeof(float));
  int*   pa    = (int*)take((size_t)NPART * NROWS * sizeof(int));
  float* diag  = (float*)take((size_t)NROWS * sizeof(float));
  float* partL = (float*)take((size_t)NCOMB * sizeof(float));
  float* partC = (float*)take((size_t)NCOMB * sizeof(float));

  prep_kernel<<<dim3((NROWS * 64) / 256), 256, 0, stream>>>(x, ph, ah, bvec);
  main_kernel<<<dim3(NROWS / BM, NSPLIT), 256, 0, stream>>>(ph, ah, bvec, pm, ps, pa, diag);
  combine_partial<<<dim3(NCOMB), 256, 0, stream>>>(pm, ps, pa, diag, partL, partC);
  final_kernel<<<1, 64, 0, stream>>>(partL, partC, out);
}